// Round 2
// baseline (393.699 us; speedup 1.0000x reference)
//
#include <hip/hip_runtime.h>
#include <hip/hip_fp16.h>
#include <math.h>

// CrossFeatureAffinityPooling on gfx950 — R8
// R6 schedule restored (two barriers/iter — R7's single-barrier regressed: same pipe
// work, more idle). New: NSPLIT=4 when ws_size permits (1024 blocks = 4 blocks/CU,
// grid was the occupancy cap at 3/CU), base-2 softmax (q pre-scaled by log2e),
// s_setprio(1) around both MFMA clusters. Runtime fallback to NSPLIT=3 layout.

typedef _Float16 v8h __attribute__((ext_vector_type(8)));
typedef float    v4f __attribute__((ext_vector_type(4)));

#define NB 4
#define NC 256
#define NS 4096
#define NG 32
#define GEPS 1e-5f
#define KSTRIDE 272            // halves per K-tile row (256 data + 16 pad)
#define KTILE   8704           // halves per 32-row K tile (17408 B = 17 KiB)
#define PSTRIDE 40             // halves per P row (32 data + 8 pad)
#define LOG2E   1.44269504f

// raw barrier: LDS-visibility only (lgkm drain), vmem stays in flight
#define ASYNC_BARRIER() asm volatile("s_waitcnt lgkmcnt(0)\n\ts_barrier" ::: "memory")

// DPP rotation-reduce within each 16-lane row (the l15 domain of MFMA quads)
template <int CTRL>
__device__ __forceinline__ float dpp_rot(float x) {
    int r = __builtin_amdgcn_update_dpp(__float_as_int(x), __float_as_int(x),
                                        CTRL, 0xF, 0xF, false);
    return __int_as_float(r);
}
__device__ __forceinline__ float row_max16(float x) {
    x = fmaxf(x, dpp_rot<0x128>(x));
    x = fmaxf(x, dpp_rot<0x124>(x));
    x = fmaxf(x, dpp_rot<0x122>(x));
    x = fmaxf(x, dpp_rot<0x121>(x));
    return x;
}
__device__ __forceinline__ float row_sum16(float x) {
    x = x + dpp_rot<0x128>(x);
    x = x + dpp_rot<0x124>(x);
    x = x + dpp_rot<0x122>(x);
    x = x + dpp_rot<0x121>(x);
    return x;
}

// ---------------- K0: convert weights into MFMA-frag order (W only) --------
__global__ __launch_bounds__(256) void k_convert(const float* __restrict__ Wh,
    const float* __restrict__ Wu, _Float16* __restrict__ Wh16, _Float16* __restrict__ Wu16)
{
    const int i = blockIdx.x * 256 + threadIdx.x;   // i < NC*NC
    const int o = i >> 8, c = i & 255;
    const int idx = ((((o >> 4) * 8 + (c >> 5)) * 4 + ((c >> 3) & 3)) * 16
                     + (o & 15)) * 8 + (c & 7);
    Wh16[idx] = (_Float16)Wh[i];
    Wu16[idx] = (_Float16)Wu[i];
}

// ---------------- K1: q^T / k^T GEMM (+ fused Uh materialization) ----------
__global__ __launch_bounds__(256) void k_qkgemm(const float* __restrict__ Hand,
    const float* __restrict__ U, const _Float16* __restrict__ Wh16,
    const _Float16* __restrict__ Wu16, const float* __restrict__ WHb,
    const float* __restrict__ WUb, _Float16* __restrict__ qT,
    _Float16* __restrict__ kTsw, _Float16* __restrict__ Uh)
{
    const int nt = blockIdx.x, b = blockIdx.y, z = blockIdx.z;
    const float*    X    = z ? U    : Hand;
    const _Float16* W    = z ? Wu16 : Wh16;
    const float*    bias = z ? WUb  : WHb;

    const int tid = threadIdx.x, w = tid >> 6, lane = tid & 63;
    const int q4 = lane >> 4, l15 = lane & 15;
    const int n = nt * 64 + w * 16 + l15;

    const float* Xcol = X + (size_t)b * NC * NS + n;
    v8h A[8];
#pragma unroll
    for (int kc = 0; kc < 8; ++kc) {
        const int c0 = kc * 32 + q4 * 8;
        v8h a;
#pragma unroll
        for (int j = 0; j < 8; ++j) a[j] = (_Float16)Xcol[(size_t)(c0 + j) * NS];
        A[kc] = a;
    }

    // fused: z=1 blocks hold U^T[n][c] fp16 frags -> write Uh[b][c][n]
    if (z == 1) {
        _Float16* ub = Uh + (size_t)b * NC * NS + n;
#pragma unroll
        for (int kc = 0; kc < 8; ++kc) {
            const int c0 = kc * 32 + q4 * 8;
#pragma unroll
            for (int j = 0; j < 8; ++j) ub[(size_t)(c0 + j) * NS] = A[kc][j];
        }
    }

#pragma unroll 4
    for (int osub = 0; osub < 16; ++osub) {
        const int o = osub * 16 + l15;
        v4f acc = {0.f, 0.f, 0.f, 0.f};
#pragma unroll
        for (int kc = 0; kc < 8; ++kc) {
            // pre-swizzled W: wave reads 1 KB contiguous, lane-coalesced b128
            const v8h bf = *(const v8h*)(W + ((size_t)(osub * 8 + kc) * 64 + lane) * 8);
            acc = __builtin_amdgcn_mfma_f32_16x16x32_f16(A[kc], bf, acc, 0, 0, 0);
        }
        const float bv = bias[o];
        if (z == 0) {
            // q scaled by log2e -> softmax runs in base-2 (raw v_exp_f32)
            _Float16* orow = qT + ((size_t)b * NS + nt * 64 + w * 16 + q4 * 4) * NC + o;
#pragma unroll
            for (int r = 0; r < 4; ++r)
                orow[(size_t)r * NC] = (_Float16)((acc[r] + bv) * LOG2E);
        } else {
            _Float16* kb = kTsw + (size_t)b * 128 * KTILE;
#pragma unroll
            for (int r = 0; r < 4; ++r) {
                const int m = nt * 64 + w * 16 + q4 * 4 + r;
                kb[(size_t)(m >> 5) * KTILE + (m & 31) * KSTRIDE + o] = (_Float16)(acc[r] + bv);
            }
        }
    }
}

// ---------------- K2: flash attention partial, R6 two-barrier pipeline -----
template <int NSPL>
__global__ __launch_bounds__(256, 4) void k_attn(const _Float16* __restrict__ qT,
    const _Float16* __restrict__ kTsw, const _Float16* __restrict__ Uh,
    _Float16* __restrict__ Ppart, float* __restrict__ mstat, float* __restrict__ lstat)
{
    const int b  = blockIdx.x;
    const int nt = blockIdx.y;
    const int s  = blockIdx.z;
    const int t0 = (s * 128) / NSPL;
    const int t1 = ((s + 1) * 128) / NSPL;

    __shared__ __align__(16) _Float16 Klds[2][KTILE];     // 2 x 17 KiB, padded rows
    __shared__ __align__(16) _Float16 Plds[64 * PSTRIDE]; // 5 KiB, padded rows
    __shared__ __align__(16) float alphaS[64];

    const int tid = threadIdx.x, w = tid >> 6, lane = tid & 63;
    const int q4 = lane >> 4, l15 = lane & 15;

    const _Float16* kTb = kTsw + (size_t)b * 128 * KTILE;
    const _Float16* Uhb = Uh + (size_t)b * NC * NS;

    // prologue: DMA K[t0] -> buf (t0&1). 17 chunks of 1 KiB; each wave copies 5
    // via (w*5+j) mod 17 (chunks 0..2 double-copied -> uniform per-wave vmcnt).
    {
        const _Float16* src = kTb + (size_t)t0 * KTILE;
#pragma unroll
        for (int j = 0; j < 5; ++j) {
            const int ch = (w * 5 + j) % 17;
            __builtin_amdgcn_global_load_lds(
                (const __attribute__((address_space(1))) void*)(src + ch * 512 + lane * 8),
                (__attribute__((address_space(3))) void*)(&Klds[t0 & 1][ch * 512]), 16, 0, 0);
        }
    }

    v8h Q[8];
    {
        const _Float16* qrow = qT + ((size_t)b * NS + nt * 64 + w * 16 + l15) * NC;
#pragma unroll
        for (int kc = 0; kc < 8; ++kc) Q[kc] = *(const v8h*)(qrow + kc * 32 + q4 * 8);
    }

    v4f O[4][4];
#pragma unroll
    for (int i = 0; i < 4; ++i)
#pragma unroll
        for (int j = 0; j < 4; ++j) O[i][j] = (v4f){0.f, 0.f, 0.f, 0.f};
    float mi[4] = {-INFINITY, -INFINITY, -INFINITY, -INFINITY};
    float li[4] = {0.f, 0.f, 0.f, 0.f};   // lane-local partial (own cols only)

    for (int t = t0; t < t1; ++t) {
        const int p = t & 1;
        const int m0 = t * 32;

        // ---- U[t] prefetch to VGPRs ----
        v8h Ur[4];
#pragma unroll
        for (int js = 0; js < 4; ++js)
            Ur[js] = *(const v8h*)(Uhb + (size_t)(w * 64 + js * 16 + l15) * NS + m0 + q4 * 8);
        asm volatile("" ::: "memory");   // pin U-before-DMA issue order (vmcnt math)

        // ---- DMA K[t+1] into other buffer; last iter wraps (uniform counts) ----
        {
            const int tn = (t + 1 < t1) ? t + 1 : t0;
            const _Float16* src = kTb + (size_t)tn * KTILE;
#pragma unroll
            for (int j = 0; j < 5; ++j) {
                const int ch = (w * 5 + j) % 17;
                __builtin_amdgcn_global_load_lds(
                    (const __attribute__((address_space(1))) void*)(src + ch * 512 + lane * 8),
                    (__attribute__((address_space(3))) void*)(&Klds[p ^ 1][ch * 512]), 16, 0, 0);
            }
        }

        // outstanding: DMA(t)=5 oldest, U(t)=4, DMA(t+1)=5 -> retire DMA(t) only
        asm volatile("s_waitcnt vmcnt(9)" ::: "memory");
        ASYNC_BARRIER();   // K[t] resident for all; Plds consumed by all

        // ---- QK^T: 16 n-rows x 32 m per wave; plain padded-row addressing ----
        v4f sv[2];
        sv[0] = (v4f){0.f, 0.f, 0.f, 0.f};
        sv[1] = (v4f){0.f, 0.f, 0.f, 0.f};
        __builtin_amdgcn_s_setprio(1);
#pragma unroll
        for (int kc = 0; kc < 8; ++kc) {
#pragma unroll
            for (int ms = 0; ms < 2; ++ms) {
                const v8h kf = *(const v8h*)(&Klds[p][(ms * 16 + l15) * KSTRIDE
                                             + (kc * 4 + q4) * 8]);
                sv[ms] = __builtin_amdgcn_mfma_f32_16x16x32_f16(Q[kc], kf, sv[ms], 0, 0, 0);
            }
        }
        __builtin_amdgcn_s_setprio(0);

        // ---- online softmax (base-2 domain): DPP max, lane-local li ----
        float al[4];
#pragma unroll
        for (int r = 0; r < 4; ++r) {
            const float tm = row_max16(fmaxf(sv[0][r], sv[1][r]));
            const float mn = fmaxf(mi[r], tm);
            al[r] = __builtin_amdgcn_exp2f(mi[r] - mn);
            mi[r] = mn;
            const float p0 = __builtin_amdgcn_exp2f(sv[0][r] - mn);
            const float p1 = __builtin_amdgcn_exp2f(sv[1][r] - mn);
            sv[0][r] = p0; sv[1][r] = p1;
            li[r] = li[r] * al[r] + p0 + p1;   // own 2 cols; reduced after loop
        }
        if (l15 == 0) {
#pragma unroll
            for (int r = 0; r < 4; ++r) alphaS[w * 16 + q4 * 4 + r] = al[r];
        }
        // P -> LDS fp16, plain padded rows (stride 40 halves)
#pragma unroll
        for (int ms = 0; ms < 2; ++ms)
#pragma unroll
            for (int r = 0; r < 4; ++r) {
                const int row = w * 16 + q4 * 4 + r;
                Plds[row * PSTRIDE + ms * 16 + l15] = (_Float16)sv[ms][r];
            }
        ASYNC_BARRIER();   // P/alpha visible; K[t] reads retired

        // ---- O = O*alpha + P x U ----
#pragma unroll
        for (int is = 0; is < 4; ++is) {
            const float4 av = *(const float4*)&alphaS[is * 16 + q4 * 4];
            const v4f aa = {av.x, av.y, av.z, av.w};
#pragma unroll
            for (int js = 0; js < 4; ++js) O[is][js] *= aa;
        }
        __builtin_amdgcn_s_setprio(1);
#pragma unroll
        for (int is = 0; is < 4; ++is) {
            const v8h Pf = *(const v8h*)(&Plds[(is * 16 + l15) * PSTRIDE + q4 * 8]);
#pragma unroll
            for (int js = 0; js < 4; ++js)
                O[is][js] = __builtin_amdgcn_mfma_f32_16x16x32_f16(Pf, Ur[js], O[is][js], 0, 0, 0);
        }
        __builtin_amdgcn_s_setprio(0);
    }

    // drain wrap DMA before LDS could be reassigned at s_endpgm
    asm volatile("s_waitcnt vmcnt(0)" ::: "memory");

    // ---- epilogue: reduce li across the quad-row, write stats + raw O ----
#pragma unroll
    for (int r = 0; r < 4; ++r) li[r] = row_sum16(li[r]);
    if (l15 == 0) {
#pragma unroll
        for (int r = 0; r < 4; ++r) {
            const int n = nt * 64 + w * 16 + q4 * 4 + r;
            mstat[(size_t)(s * NB + b) * NS + n] = mi[r];
            lstat[(size_t)(s * NB + b) * NS + n] = li[r];
        }
    }
#pragma unroll
    for (int is = 0; is < 4; ++is)
#pragma unroll
        for (int js = 0; js < 4; ++js)
#pragma unroll
            for (int r = 0; r < 4; ++r) {
                _Float16* dst = Ppart + ((size_t)(s * NB + b) * NS + nt * 64 + is * 16
                                         + q4 * 4 + r) * NC + w * 64 + js * 16 + l15;
                __builtin_nontemporal_store((_Float16)O[is][js][r], dst);
            }
}

// ---------------- K3: merge NSPL partials -> fp32 Opre + fused GN sums -----
// exp2 domain (m stats are log2-scaled scores).
template <int NSPL>
__global__ __launch_bounds__(256) void k_merge(const _Float16* __restrict__ Pp,
    const float* __restrict__ mstat, const float* __restrict__ lstat,
    float* __restrict__ Opre, float* __restrict__ statacc)
{
    const int b = blockIdx.y, tid = threadIdx.x;
    const int n = blockIdx.x * 8 + (tid >> 5);
    const int c0 = (tid & 31) * 8;            // == group (tid&31) exactly
    const size_t nb = (size_t)b * NS + n;
    const size_t SP = (size_t)NB * NS;

    float m[NSPL], l[NSPL];
#pragma unroll
    for (int sp = 0; sp < NSPL; ++sp) {
        m[sp] = mstat[sp * SP + nb];
        l[sp] = lstat[sp * SP + nb];
    }
    float M = m[0];
#pragma unroll
    for (int sp = 1; sp < NSPL; ++sp) M = fmaxf(M, m[sp]);
    float denom = 0.f, wgt[NSPL];
#pragma unroll
    for (int sp = 0; sp < NSPL; ++sp) {
        wgt[sp] = exp2f(m[sp] - M);
        denom += wgt[sp] * l[sp];
    }
    const float inv = 1.f / denom;

    const size_t base = nb * NC + c0;
    float v[8] = {0.f, 0.f, 0.f, 0.f, 0.f, 0.f, 0.f, 0.f};
#pragma unroll
    for (int sp = 0; sp < NSPL; ++sp) {
        const float ws = wgt[sp] * inv;
        const v8h pv = *(const v8h*)(Pp + (size_t)sp * SP * NC + base);
#pragma unroll
        for (int j = 0; j < 8; ++j) v[j] += ws * (float)pv[j];
    }
    float s1 = 0.f, s2 = 0.f;
#pragma unroll
    for (int j = 0; j < 8; ++j) { s1 += v[j]; s2 += v[j] * v[j]; }
    *(float4*)(Opre + base)     = make_float4(v[0], v[1], v[2], v[3]);
    *(float4*)(Opre + base + 4) = make_float4(v[4], v[5], v[6], v[7]);

    __shared__ float r1[256], r2[256];
    r1[tid] = s1; r2[tid] = s2;
    __syncthreads();
    if (tid < 32) {
        float a = 0.f, q = 0.f;
#pragma unroll
        for (int k = 0; k < 8; ++k) { a += r1[tid + 32 * k]; q += r2[tid + 32 * k]; }
        atomicAdd(&statacc[(b * NG + tid) * 2 + 0], a);
        atomicAdd(&statacc[(b * NG + tid) * 2 + 1], q);
    }
}

// ---------------- K4: apply GN + residual, [b][n][c] -> [b][c][n] ----------
__global__ __launch_bounds__(256) void k_gnapply(const float* __restrict__ Opre,
    const float* __restrict__ Hand, const float* __restrict__ gnw,
    const float* __restrict__ gnb, const float* __restrict__ statacc,
    float* __restrict__ out)
{
    const int nt = blockIdx.x, ct = blockIdx.y, b = blockIdx.z;
    __shared__ float buf[64 * 65];
    const int tid = threadIdx.x;
    {
        const int nr = tid >> 4, c4 = (tid & 15) * 4;
#pragma unroll
        for (int k = 0; k < 4; ++k) {
            const int n = nr + 16 * k;
            const float4 v = *(const float4*)(Opre + ((size_t)b * NS + nt * 64 + n) * NC
                                              + ct * 64 + c4);
            buf[n * 65 + c4 + 0] = v.x; buf[n * 65 + c4 + 1] = v.y;
            buf[n * 65 + c4 + 2] = v.z; buf[n * 65 + c4 + 3] = v.w;
        }
    }
    __syncthreads();
    const int nw = tid & 63, c0 = tid >> 6;
#pragma unroll
    for (int k = 0; k < 16; ++k) {
        const int cl = c0 + 4 * k;
        const int c  = ct * 64 + cl;
        const int g  = c >> 3;
        const float s1   = statacc[(b * NG + g) * 2 + 0];
        const float s2   = statacc[(b * NG + g) * 2 + 1];
        const float mean = s1 * (1.f / 32768.f);
        const float var  = s2 * (1.f / 32768.f) - mean * mean;
        const float rstd = rsqrtf(var + GEPS);
        const size_t oidx = ((size_t)b * NC + c) * NS + nt * 64 + nw;
        out[oidx] = (buf[nw * 65 + cl] - mean) * rstd * gnw[c] + gnb[c] + Hand[oidx];
    }
}

extern "C" void kernel_launch(void* const* d_in, const int* in_sizes, int n_in,
                              void* d_out, int out_size, void* d_ws, size_t ws_size,
                              hipStream_t stream)
{
    const float* Hand = (const float*)d_in[0];
    const float* U    = (const float*)d_in[1];
    const float* WHw  = (const float*)d_in[2];
    const float* WHb  = (const float*)d_in[3];
    const float* WUw  = (const float*)d_in[4];
    const float* WUb  = (const float*)d_in[5];
    const float* gnw  = (const float*)d_in[6];
    const float* gnb  = (const float*)d_in[7];
    float* out = (float*)d_out;

    // nsplit=4 needs 60,033,024 B; fall back to the proven nsplit=3 layout (49.1 MiB)
    // if the workspace is tighter than that.
    const size_t NEED4 = 25952256u + 2u * 262144u + 2048u + 33554432u;
    const int nsplit = (ws_size >= NEED4) ? 4 : 3;

    char* ws = (char*)d_ws;
    _Float16* qT     = (_Float16*)(ws);                  //  8 MiB   [b][n][c]
    _Float16* kTsw   = (_Float16*)(ws + 8388608);        //  8.5 MiB padded 32-row tiles
    _Float16* Uh     = (_Float16*)(ws + 17301504);       //  8 MiB   [b][c][m]
    _Float16* Wh16   = (_Float16*)(ws + 25690112);       //  128 KiB (frag-order)
    _Float16* Wu16   = (_Float16*)(ws + 25821184);       //  128 KiB (frag-order)
    const size_t statB = (size_t)nsplit * NB * NS * 4;   // per stat array
    float*    mstat  = (float*)(ws + 25952256);
    float*    lstat  = (float*)(ws + 25952256 + statB);
    float*    statacc= (float*)(ws + 25952256 + 2 * statB);
    _Float16* Ppart  = (_Float16*)(ws + 25952256 + 2 * statB + 2048);
    float*    Opre   = (float*)(ws);                     //  16 MiB alias (qT+kTsw dead)

    hipMemsetAsync(statacc, 0, NB * NG * 2 * sizeof(float), stream);
    k_convert<<<dim3((NC * NC) / 256), 256, 0, stream>>>(WHw, WUw, Wh16, Wu16);
    k_qkgemm <<<dim3(64, NB, 2), 256, 0, stream>>>(Hand, U, Wh16, Wu16, WHb, WUb, qT, kTsw, Uh);
    if (nsplit == 4) {
        k_attn<4> <<<dim3(NB, 64, 4), 256, 0, stream>>>(qT, kTsw, Uh, Ppart, mstat, lstat);
        k_merge<4><<<dim3(NS / 8, NB), 256, 0, stream>>>(Ppart, mstat, lstat, Opre, statacc);
    } else {
        k_attn<3> <<<dim3(NB, 64, 3), 256, 0, stream>>>(qT, kTsw, Uh, Ppart, mstat, lstat);
        k_merge<3><<<dim3(NS / 8, NB), 256, 0, stream>>>(Ppart, mstat, lstat, Opre, statacc);
    }
    k_gnapply<<<dim3(64, 4, NB), 256, 0, stream>>>(Opre, Hand, gnw, gnb, statacc, out);
}

// Round 3
// 302.488 us; speedup vs baseline: 1.3015x; 1.3015x over previous
//
#include <hip/hip_runtime.h>
#include <hip/hip_fp16.h>
#include <math.h>

// CrossFeatureAffinityPooling on gfx950 — R9
// R8 post-mortem: __launch_bounds__(256,4) forced VGPR 84->64 -> register spills
// (FETCH 21MB->455MB of scratch reloads). Fix: keep NSPLIT=4 grid (1024 blocks =
// 4 blocks/CU; occupancy DID rise 31->44%) but restore (256,3) bound — 84 VGPR
// still allows 4 waves/SIMD (step is at 128), no spills.

typedef _Float16 v8h __attribute__((ext_vector_type(8)));
typedef float    v4f __attribute__((ext_vector_type(4)));

#define NB 4
#define NC 256
#define NS 4096
#define NG 32
#define GEPS 1e-5f
#define KSTRIDE 272            // halves per K-tile row (256 data + 16 pad)
#define KTILE   8704           // halves per 32-row K tile (17408 B = 17 KiB)
#define PSTRIDE 40             // halves per P row (32 data + 8 pad)
#define LOG2E   1.44269504f

// raw barrier: LDS-visibility only (lgkm drain), vmem stays in flight
#define ASYNC_BARRIER() asm volatile("s_waitcnt lgkmcnt(0)\n\ts_barrier" ::: "memory")

// DPP rotation-reduce within each 16-lane row (the l15 domain of MFMA quads)
template <int CTRL>
__device__ __forceinline__ float dpp_rot(float x) {
    int r = __builtin_amdgcn_update_dpp(__float_as_int(x), __float_as_int(x),
                                        CTRL, 0xF, 0xF, false);
    return __int_as_float(r);
}
__device__ __forceinline__ float row_max16(float x) {
    x = fmaxf(x, dpp_rot<0x128>(x));
    x = fmaxf(x, dpp_rot<0x124>(x));
    x = fmaxf(x, dpp_rot<0x122>(x));
    x = fmaxf(x, dpp_rot<0x121>(x));
    return x;
}
__device__ __forceinline__ float row_sum16(float x) {
    x = x + dpp_rot<0x128>(x);
    x = x + dpp_rot<0x124>(x);
    x = x + dpp_rot<0x122>(x);
    x = x + dpp_rot<0x121>(x);
    return x;
}

// ---------------- K0: convert weights into MFMA-frag order (W only) --------
__global__ __launch_bounds__(256) void k_convert(const float* __restrict__ Wh,
    const float* __restrict__ Wu, _Float16* __restrict__ Wh16, _Float16* __restrict__ Wu16)
{
    const int i = blockIdx.x * 256 + threadIdx.x;   // i < NC*NC
    const int o = i >> 8, c = i & 255;
    const int idx = ((((o >> 4) * 8 + (c >> 5)) * 4 + ((c >> 3) & 3)) * 16
                     + (o & 15)) * 8 + (c & 7);
    Wh16[idx] = (_Float16)Wh[i];
    Wu16[idx] = (_Float16)Wu[i];
}

// ---------------- K1: q^T / k^T GEMM (+ fused Uh materialization) ----------
__global__ __launch_bounds__(256) void k_qkgemm(const float* __restrict__ Hand,
    const float* __restrict__ U, const _Float16* __restrict__ Wh16,
    const _Float16* __restrict__ Wu16, const float* __restrict__ WHb,
    const float* __restrict__ WUb, _Float16* __restrict__ qT,
    _Float16* __restrict__ kTsw, _Float16* __restrict__ Uh)
{
    const int nt = blockIdx.x, b = blockIdx.y, z = blockIdx.z;
    const float*    X    = z ? U    : Hand;
    const _Float16* W    = z ? Wu16 : Wh16;
    const float*    bias = z ? WUb  : WHb;

    const int tid = threadIdx.x, w = tid >> 6, lane = tid & 63;
    const int q4 = lane >> 4, l15 = lane & 15;
    const int n = nt * 64 + w * 16 + l15;

    const float* Xcol = X + (size_t)b * NC * NS + n;
    v8h A[8];
#pragma unroll
    for (int kc = 0; kc < 8; ++kc) {
        const int c0 = kc * 32 + q4 * 8;
        v8h a;
#pragma unroll
        for (int j = 0; j < 8; ++j) a[j] = (_Float16)Xcol[(size_t)(c0 + j) * NS];
        A[kc] = a;
    }

    // fused: z=1 blocks hold U^T[n][c] fp16 frags -> write Uh[b][c][n]
    if (z == 1) {
        _Float16* ub = Uh + (size_t)b * NC * NS + n;
#pragma unroll
        for (int kc = 0; kc < 8; ++kc) {
            const int c0 = kc * 32 + q4 * 8;
#pragma unroll
            for (int j = 0; j < 8; ++j) ub[(size_t)(c0 + j) * NS] = A[kc][j];
        }
    }

#pragma unroll 4
    for (int osub = 0; osub < 16; ++osub) {
        const int o = osub * 16 + l15;
        v4f acc = {0.f, 0.f, 0.f, 0.f};
#pragma unroll
        for (int kc = 0; kc < 8; ++kc) {
            // pre-swizzled W: wave reads 1 KB contiguous, lane-coalesced b128
            const v8h bf = *(const v8h*)(W + ((size_t)(osub * 8 + kc) * 64 + lane) * 8);
            acc = __builtin_amdgcn_mfma_f32_16x16x32_f16(A[kc], bf, acc, 0, 0, 0);
        }
        const float bv = bias[o];
        if (z == 0) {
            // q scaled by log2e -> softmax runs in base-2 (raw v_exp_f32)
            _Float16* orow = qT + ((size_t)b * NS + nt * 64 + w * 16 + q4 * 4) * NC + o;
#pragma unroll
            for (int r = 0; r < 4; ++r)
                orow[(size_t)r * NC] = (_Float16)((acc[r] + bv) * LOG2E);
        } else {
            _Float16* kb = kTsw + (size_t)b * 128 * KTILE;
#pragma unroll
            for (int r = 0; r < 4; ++r) {
                const int m = nt * 64 + w * 16 + q4 * 4 + r;
                kb[(size_t)(m >> 5) * KTILE + (m & 31) * KSTRIDE + o] = (_Float16)(acc[r] + bv);
            }
        }
    }
}

// ---------------- K2: flash attention partial, R6 two-barrier pipeline -----
template <int NSPL>
__global__ __launch_bounds__(256, 3) void k_attn(const _Float16* __restrict__ qT,
    const _Float16* __restrict__ kTsw, const _Float16* __restrict__ Uh,
    _Float16* __restrict__ Ppart, float* __restrict__ mstat, float* __restrict__ lstat)
{
    const int b  = blockIdx.x;
    const int nt = blockIdx.y;
    const int s  = blockIdx.z;
    const int t0 = (s * 128) / NSPL;
    const int t1 = ((s + 1) * 128) / NSPL;

    __shared__ __align__(16) _Float16 Klds[2][KTILE];     // 2 x 17 KiB, padded rows
    __shared__ __align__(16) _Float16 Plds[64 * PSTRIDE]; // 5 KiB, padded rows
    __shared__ __align__(16) float alphaS[64];

    const int tid = threadIdx.x, w = tid >> 6, lane = tid & 63;
    const int q4 = lane >> 4, l15 = lane & 15;

    const _Float16* kTb = kTsw + (size_t)b * 128 * KTILE;
    const _Float16* Uhb = Uh + (size_t)b * NC * NS;

    // prologue: DMA K[t0] -> buf (t0&1). 17 chunks of 1 KiB; each wave copies 5
    // via (w*5+j) mod 17 (chunks 0..2 double-copied -> uniform per-wave vmcnt).
    {
        const _Float16* src = kTb + (size_t)t0 * KTILE;
#pragma unroll
        for (int j = 0; j < 5; ++j) {
            const int ch = (w * 5 + j) % 17;
            __builtin_amdgcn_global_load_lds(
                (const __attribute__((address_space(1))) void*)(src + ch * 512 + lane * 8),
                (__attribute__((address_space(3))) void*)(&Klds[t0 & 1][ch * 512]), 16, 0, 0);
        }
    }

    v8h Q[8];
    {
        const _Float16* qrow = qT + ((size_t)b * NS + nt * 64 + w * 16 + l15) * NC;
#pragma unroll
        for (int kc = 0; kc < 8; ++kc) Q[kc] = *(const v8h*)(qrow + kc * 32 + q4 * 8);
    }

    v4f O[4][4];
#pragma unroll
    for (int i = 0; i < 4; ++i)
#pragma unroll
        for (int j = 0; j < 4; ++j) O[i][j] = (v4f){0.f, 0.f, 0.f, 0.f};
    float mi[4] = {-INFINITY, -INFINITY, -INFINITY, -INFINITY};
    float li[4] = {0.f, 0.f, 0.f, 0.f};   // lane-local partial (own cols only)

    for (int t = t0; t < t1; ++t) {
        const int p = t & 1;
        const int m0 = t * 32;

        // ---- U[t] prefetch to VGPRs ----
        v8h Ur[4];
#pragma unroll
        for (int js = 0; js < 4; ++js)
            Ur[js] = *(const v8h*)(Uhb + (size_t)(w * 64 + js * 16 + l15) * NS + m0 + q4 * 8);
        asm volatile("" ::: "memory");   // pin U-before-DMA issue order (vmcnt math)

        // ---- DMA K[t+1] into other buffer; last iter wraps (uniform counts) ----
        {
            const int tn = (t + 1 < t1) ? t + 1 : t0;
            const _Float16* src = kTb + (size_t)tn * KTILE;
#pragma unroll
            for (int j = 0; j < 5; ++j) {
                const int ch = (w * 5 + j) % 17;
                __builtin_amdgcn_global_load_lds(
                    (const __attribute__((address_space(1))) void*)(src + ch * 512 + lane * 8),
                    (__attribute__((address_space(3))) void*)(&Klds[p ^ 1][ch * 512]), 16, 0, 0);
            }
        }

        // outstanding: DMA(t)=5 oldest, U(t)=4, DMA(t+1)=5 -> retire DMA(t) only
        asm volatile("s_waitcnt vmcnt(9)" ::: "memory");
        ASYNC_BARRIER();   // K[t] resident for all; Plds consumed by all

        // ---- QK^T: 16 n-rows x 32 m per wave; plain padded-row addressing ----
        v4f sv[2];
        sv[0] = (v4f){0.f, 0.f, 0.f, 0.f};
        sv[1] = (v4f){0.f, 0.f, 0.f, 0.f};
        __builtin_amdgcn_s_setprio(1);
#pragma unroll
        for (int kc = 0; kc < 8; ++kc) {
#pragma unroll
            for (int ms = 0; ms < 2; ++ms) {
                const v8h kf = *(const v8h*)(&Klds[p][(ms * 16 + l15) * KSTRIDE
                                             + (kc * 4 + q4) * 8]);
                sv[ms] = __builtin_amdgcn_mfma_f32_16x16x32_f16(Q[kc], kf, sv[ms], 0, 0, 0);
            }
        }
        __builtin_amdgcn_s_setprio(0);

        // ---- online softmax (base-2 domain): DPP max, lane-local li ----
        float al[4];
#pragma unroll
        for (int r = 0; r < 4; ++r) {
            const float tm = row_max16(fmaxf(sv[0][r], sv[1][r]));
            const float mn = fmaxf(mi[r], tm);
            al[r] = __builtin_amdgcn_exp2f(mi[r] - mn);
            mi[r] = mn;
            const float p0 = __builtin_amdgcn_exp2f(sv[0][r] - mn);
            const float p1 = __builtin_amdgcn_exp2f(sv[1][r] - mn);
            sv[0][r] = p0; sv[1][r] = p1;
            li[r] = li[r] * al[r] + p0 + p1;   // own 2 cols; reduced after loop
        }
        if (l15 == 0) {
#pragma unroll
            for (int r = 0; r < 4; ++r) alphaS[w * 16 + q4 * 4 + r] = al[r];
        }
        // P -> LDS fp16, plain padded rows (stride 40 halves)
#pragma unroll
        for (int ms = 0; ms < 2; ++ms)
#pragma unroll
            for (int r = 0; r < 4; ++r) {
                const int row = w * 16 + q4 * 4 + r;
                Plds[row * PSTRIDE + ms * 16 + l15] = (_Float16)sv[ms][r];
            }
        ASYNC_BARRIER();   // P/alpha visible; K[t] reads retired

        // ---- O = O*alpha + P x U ----
#pragma unroll
        for (int is = 0; is < 4; ++is) {
            const float4 av = *(const float4*)&alphaS[is * 16 + q4 * 4];
            const v4f aa = {av.x, av.y, av.z, av.w};
#pragma unroll
            for (int js = 0; js < 4; ++js) O[is][js] *= aa;
        }
        __builtin_amdgcn_s_setprio(1);
#pragma unroll
        for (int is = 0; is < 4; ++is) {
            const v8h Pf = *(const v8h*)(&Plds[(is * 16 + l15) * PSTRIDE + q4 * 8]);
#pragma unroll
            for (int js = 0; js < 4; ++js)
                O[is][js] = __builtin_amdgcn_mfma_f32_16x16x32_f16(Pf, Ur[js], O[is][js], 0, 0, 0);
        }
        __builtin_amdgcn_s_setprio(0);
    }

    // drain wrap DMA before LDS could be reassigned at s_endpgm
    asm volatile("s_waitcnt vmcnt(0)" ::: "memory");

    // ---- epilogue: reduce li across the quad-row, write stats + raw O ----
#pragma unroll
    for (int r = 0; r < 4; ++r) li[r] = row_sum16(li[r]);
    if (l15 == 0) {
#pragma unroll
        for (int r = 0; r < 4; ++r) {
            const int n = nt * 64 + w * 16 + q4 * 4 + r;
            mstat[(size_t)(s * NB + b) * NS + n] = mi[r];
            lstat[(size_t)(s * NB + b) * NS + n] = li[r];
        }
    }
#pragma unroll
    for (int is = 0; is < 4; ++is)
#pragma unroll
        for (int js = 0; js < 4; ++js)
#pragma unroll
            for (int r = 0; r < 4; ++r) {
                _Float16* dst = Ppart + ((size_t)(s * NB + b) * NS + nt * 64 + is * 16
                                         + q4 * 4 + r) * NC + w * 64 + js * 16 + l15;
                __builtin_nontemporal_store((_Float16)O[is][js][r], dst);
            }
}

// ---------------- K3: merge NSPL partials -> fp32 Opre + fused GN sums -----
// exp2 domain (m stats are log2-scaled scores).
template <int NSPL>
__global__ __launch_bounds__(256) void k_merge(const _Float16* __restrict__ Pp,
    const float* __restrict__ mstat, const float* __restrict__ lstat,
    float* __restrict__ Opre, float* __restrict__ statacc)
{
    const int b = blockIdx.y, tid = threadIdx.x;
    const int n = blockIdx.x * 8 + (tid >> 5);
    const int c0 = (tid & 31) * 8;            // == group (tid&31) exactly
    const size_t nb = (size_t)b * NS + n;
    const size_t SP = (size_t)NB * NS;

    float m[NSPL], l[NSPL];
#pragma unroll
    for (int sp = 0; sp < NSPL; ++sp) {
        m[sp] = mstat[sp * SP + nb];
        l[sp] = lstat[sp * SP + nb];
    }
    float M = m[0];
#pragma unroll
    for (int sp = 1; sp < NSPL; ++sp) M = fmaxf(M, m[sp]);
    float denom = 0.f, wgt[NSPL];
#pragma unroll
    for (int sp = 0; sp < NSPL; ++sp) {
        wgt[sp] = exp2f(m[sp] - M);
        denom += wgt[sp] * l[sp];
    }
    const float inv = 1.f / denom;

    const size_t base = nb * NC + c0;
    float v[8] = {0.f, 0.f, 0.f, 0.f, 0.f, 0.f, 0.f, 0.f};
#pragma unroll
    for (int sp = 0; sp < NSPL; ++sp) {
        const float ws = wgt[sp] * inv;
        const v8h pv = *(const v8h*)(Pp + (size_t)sp * SP * NC + base);
#pragma unroll
        for (int j = 0; j < 8; ++j) v[j] += ws * (float)pv[j];
    }
    float s1 = 0.f, s2 = 0.f;
#pragma unroll
    for (int j = 0; j < 8; ++j) { s1 += v[j]; s2 += v[j] * v[j]; }
    *(float4*)(Opre + base)     = make_float4(v[0], v[1], v[2], v[3]);
    *(float4*)(Opre + base + 4) = make_float4(v[4], v[5], v[6], v[7]);

    __shared__ float r1[256], r2[256];
    r1[tid] = s1; r2[tid] = s2;
    __syncthreads();
    if (tid < 32) {
        float a = 0.f, q = 0.f;
#pragma unroll
        for (int k = 0; k < 8; ++k) { a += r1[tid + 32 * k]; q += r2[tid + 32 * k]; }
        atomicAdd(&statacc[(b * NG + tid) * 2 + 0], a);
        atomicAdd(&statacc[(b * NG + tid) * 2 + 1], q);
    }
}

// ---------------- K4: apply GN + residual, [b][n][c] -> [b][c][n] ----------
__global__ __launch_bounds__(256) void k_gnapply(const float* __restrict__ Opre,
    const float* __restrict__ Hand, const float* __restrict__ gnw,
    const float* __restrict__ gnb, const float* __restrict__ statacc,
    float* __restrict__ out)
{
    const int nt = blockIdx.x, ct = blockIdx.y, b = blockIdx.z;
    __shared__ float buf[64 * 65];
    const int tid = threadIdx.x;
    {
        const int nr = tid >> 4, c4 = (tid & 15) * 4;
#pragma unroll
        for (int k = 0; k < 4; ++k) {
            const int n = nr + 16 * k;
            const float4 v = *(const float4*)(Opre + ((size_t)b * NS + nt * 64 + n) * NC
                                              + ct * 64 + c4);
            buf[n * 65 + c4 + 0] = v.x; buf[n * 65 + c4 + 1] = v.y;
            buf[n * 65 + c4 + 2] = v.z; buf[n * 65 + c4 + 3] = v.w;
        }
    }
    __syncthreads();
    const int nw = tid & 63, c0 = tid >> 6;
#pragma unroll
    for (int k = 0; k < 16; ++k) {
        const int cl = c0 + 4 * k;
        const int c  = ct * 64 + cl;
        const int g  = c >> 3;
        const float s1   = statacc[(b * NG + g) * 2 + 0];
        const float s2   = statacc[(b * NG + g) * 2 + 1];
        const float mean = s1 * (1.f / 32768.f);
        const float var  = s2 * (1.f / 32768.f) - mean * mean;
        const float rstd = rsqrtf(var + GEPS);
        const size_t oidx = ((size_t)b * NC + c) * NS + nt * 64 + nw;
        out[oidx] = (buf[nw * 65 + cl] - mean) * rstd * gnw[c] + gnb[c] + Hand[oidx];
    }
}

extern "C" void kernel_launch(void* const* d_in, const int* in_sizes, int n_in,
                              void* d_out, int out_size, void* d_ws, size_t ws_size,
                              hipStream_t stream)
{
    const float* Hand = (const float*)d_in[0];
    const float* U    = (const float*)d_in[1];
    const float* WHw  = (const float*)d_in[2];
    const float* WHb  = (const float*)d_in[3];
    const float* WUw  = (const float*)d_in[4];
    const float* WUb  = (const float*)d_in[5];
    const float* gnw  = (const float*)d_in[6];
    const float* gnb  = (const float*)d_in[7];
    float* out = (float*)d_out;

    // nsplit=4 needs 60,033,024 B; fall back to the proven nsplit=3 layout (49.1 MiB)
    // if the workspace is tighter than that.
    const size_t NEED4 = 25952256u + 2u * 262144u + 2048u + 33554432u;
    const int nsplit = (ws_size >= NEED4) ? 4 : 3;

    char* ws = (char*)d_ws;
    _Float16* qT     = (_Float16*)(ws);                  //  8 MiB   [b][n][c]
    _Float16* kTsw   = (_Float16*)(ws + 8388608);        //  8.5 MiB padded 32-row tiles
    _Float16* Uh     = (_Float16*)(ws + 17301504);       //  8 MiB   [b][c][m]
    _Float16* Wh16   = (_Float16*)(ws + 25690112);       //  128 KiB (frag-order)
    _Float16* Wu16   = (_Float16*)(ws + 25821184);       //  128 KiB (frag-order)
    const size_t statB = (size_t)nsplit * NB * NS * 4;   // per stat array
    float*    mstat  = (float*)(ws + 25952256);
    float*    lstat  = (float*)(ws + 25952256 + statB);
    float*    statacc= (float*)(ws + 25952256 + 2 * statB);
    _Float16* Ppart  = (_Float16*)(ws + 25952256 + 2 * statB + 2048);
    float*    Opre   = (float*)(ws);                     //  16 MiB alias (qT+kTsw dead)

    hipMemsetAsync(statacc, 0, NB * NG * 2 * sizeof(float), stream);
    k_convert<<<dim3((NC * NC) / 256), 256, 0, stream>>>(WHw, WUw, Wh16, Wu16);
    k_qkgemm <<<dim3(64, NB, 2), 256, 0, stream>>>(Hand, U, Wh16, Wu16, WHb, WUb, qT, kTsw, Uh);
    if (nsplit == 4) {
        k_attn<4> <<<dim3(NB, 64, 4), 256, 0, stream>>>(qT, kTsw, Uh, Ppart, mstat, lstat);
        k_merge<4><<<dim3(NS / 8, NB), 256, 0, stream>>>(Ppart, mstat, lstat, Opre, statacc);
    } else {
        k_attn<3> <<<dim3(NB, 64, 3), 256, 0, stream>>>(qT, kTsw, Uh, Ppart, mstat, lstat);
        k_merge<3><<<dim3(NS / 8, NB), 256, 0, stream>>>(Ppart, mstat, lstat, Opre, statacc);
    }
    k_gnapply<<<dim3(64, 4, NB), 256, 0, stream>>>(Opre, Hand, gnw, gnb, statacc, out);
}

// Round 4
// 297.024 us; speedup vs baseline: 1.3255x; 1.0184x over previous
//
#include <hip/hip_runtime.h>
#include <hip/hip_fp16.h>
#include <math.h>

// CrossFeatureAffinityPooling on gfx950 — R10
// R9 post-mortem: nsplit=4 ran as 768-resident + 256-block tail (occupancy 23% =
// two-phase average) -> LDS 40448 B did NOT fit 4 blocks/CU in practice.
// Fix: K tiles stored UNPADDED (256-half rows) with XOR bank swizzle
// (col ^= (row&7)<<3 halves), pre-swizzled at k_qkgemm store, DMA'd linearly
// (16 x 1KiB chunks = 4/wave exactly), read with the same XOR in QK^T.
// LDS 40448 -> 38144 B => 4 blocks/CU genuinely fit; grid 1024 = zero tail.

typedef _Float16 v8h __attribute__((ext_vector_type(8)));
typedef float    v4f __attribute__((ext_vector_type(4)));

#define NB 4
#define NC 256
#define NS 4096
#define NG 32
#define GEPS 1e-5f
#define KT 8192                // halves per 32-row K tile (32*256, unpadded, swizzled)
#define PSTRIDE 40             // halves per P row (32 data + 8 pad)
#define LOG2E   1.44269504f

// raw barrier: LDS-visibility only (lgkm drain), vmem stays in flight
#define ASYNC_BARRIER() asm volatile("s_waitcnt lgkmcnt(0)\n\ts_barrier" ::: "memory")

// DPP rotation-reduce within each 16-lane row (the l15 domain of MFMA quads)
template <int CTRL>
__device__ __forceinline__ float dpp_rot(float x) {
    int r = __builtin_amdgcn_update_dpp(__float_as_int(x), __float_as_int(x),
                                        CTRL, 0xF, 0xF, false);
    return __int_as_float(r);
}
__device__ __forceinline__ float row_max16(float x) {
    x = fmaxf(x, dpp_rot<0x128>(x));
    x = fmaxf(x, dpp_rot<0x124>(x));
    x = fmaxf(x, dpp_rot<0x122>(x));
    x = fmaxf(x, dpp_rot<0x121>(x));
    return x;
}
__device__ __forceinline__ float row_sum16(float x) {
    x = x + dpp_rot<0x128>(x);
    x = x + dpp_rot<0x124>(x);
    x = x + dpp_rot<0x122>(x);
    x = x + dpp_rot<0x121>(x);
    return x;
}

// ---------------- K0: convert weights into MFMA-frag order (W only) --------
__global__ __launch_bounds__(256) void k_convert(const float* __restrict__ Wh,
    const float* __restrict__ Wu, _Float16* __restrict__ Wh16, _Float16* __restrict__ Wu16)
{
    const int i = blockIdx.x * 256 + threadIdx.x;   // i < NC*NC
    const int o = i >> 8, c = i & 255;
    const int idx = ((((o >> 4) * 8 + (c >> 5)) * 4 + ((c >> 3) & 3)) * 16
                     + (o & 15)) * 8 + (c & 7);
    Wh16[idx] = (_Float16)Wh[i];
    Wu16[idx] = (_Float16)Wu[i];
}

// ---------------- K1: q^T / k^T GEMM (+ fused Uh materialization) ----------
__global__ __launch_bounds__(256) void k_qkgemm(const float* __restrict__ Hand,
    const float* __restrict__ U, const _Float16* __restrict__ Wh16,
    const _Float16* __restrict__ Wu16, const float* __restrict__ WHb,
    const float* __restrict__ WUb, _Float16* __restrict__ qT,
    _Float16* __restrict__ kTsw, _Float16* __restrict__ Uh)
{
    const int nt = blockIdx.x, b = blockIdx.y, z = blockIdx.z;
    const float*    X    = z ? U    : Hand;
    const _Float16* W    = z ? Wu16 : Wh16;
    const float*    bias = z ? WUb  : WHb;

    const int tid = threadIdx.x, w = tid >> 6, lane = tid & 63;
    const int q4 = lane >> 4, l15 = lane & 15;
    const int n = nt * 64 + w * 16 + l15;

    const float* Xcol = X + (size_t)b * NC * NS + n;
    v8h A[8];
#pragma unroll
    for (int kc = 0; kc < 8; ++kc) {
        const int c0 = kc * 32 + q4 * 8;
        v8h a;
#pragma unroll
        for (int j = 0; j < 8; ++j) a[j] = (_Float16)Xcol[(size_t)(c0 + j) * NS];
        A[kc] = a;
    }

    // fused: z=1 blocks hold U^T[n][c] fp16 frags -> write Uh[b][c][n]
    if (z == 1) {
        _Float16* ub = Uh + (size_t)b * NC * NS + n;
#pragma unroll
        for (int kc = 0; kc < 8; ++kc) {
            const int c0 = kc * 32 + q4 * 8;
#pragma unroll
            for (int j = 0; j < 8; ++j) ub[(size_t)(c0 + j) * NS] = A[kc][j];
        }
    }

#pragma unroll 4
    for (int osub = 0; osub < 16; ++osub) {
        const int o = osub * 16 + l15;
        v4f acc = {0.f, 0.f, 0.f, 0.f};
#pragma unroll
        for (int kc = 0; kc < 8; ++kc) {
            // pre-swizzled W: wave reads 1 KB contiguous, lane-coalesced b128
            const v8h bf = *(const v8h*)(W + ((size_t)(osub * 8 + kc) * 64 + lane) * 8);
            acc = __builtin_amdgcn_mfma_f32_16x16x32_f16(A[kc], bf, acc, 0, 0, 0);
        }
        const float bv = bias[o];
        if (z == 0) {
            // q scaled by log2e -> softmax runs in base-2 (raw v_exp_f32)
            _Float16* orow = qT + ((size_t)b * NS + nt * 64 + w * 16 + q4 * 4) * NC + o;
#pragma unroll
            for (int r = 0; r < 4; ++r)
                orow[(size_t)r * NC] = (_Float16)((acc[r] + bv) * LOG2E);
        } else {
            // K stored pre-swizzled: tile (m>>5), row (m&31), col o ^ ((m&7)<<3)
            _Float16* kb = kTsw + (size_t)b * NS * NC;
#pragma unroll
            for (int r = 0; r < 4; ++r) {
                const int m = nt * 64 + w * 16 + q4 * 4 + r;
                kb[(size_t)(m >> 5) * KT + (m & 31) * 256 + (o ^ ((m & 7) << 3))]
                    = (_Float16)(acc[r] + bv);
            }
        }
    }
}

// ---------------- K2: flash attention partial, R6 two-barrier pipeline -----
template <int NSPL>
__global__ __launch_bounds__(256, 3) void k_attn(const _Float16* __restrict__ qT,
    const _Float16* __restrict__ kTsw, const _Float16* __restrict__ Uh,
    _Float16* __restrict__ Ppart, float* __restrict__ mstat, float* __restrict__ lstat)
{
    const int b  = blockIdx.x;
    const int nt = blockIdx.y;
    const int s  = blockIdx.z;
    const int t0 = (s * 128) / NSPL;
    const int t1 = ((s + 1) * 128) / NSPL;

    __shared__ __align__(16) _Float16 Klds[2][KT];        // 2 x 16 KiB, swizzled rows
    __shared__ __align__(16) _Float16 Plds[64 * PSTRIDE]; // 5 KiB, padded rows
    __shared__ __align__(16) float alphaS[64];

    const int tid = threadIdx.x, w = tid >> 6, lane = tid & 63;
    const int q4 = lane >> 4, l15 = lane & 15;

    const _Float16* kTb = kTsw + (size_t)b * NS * NC;
    const _Float16* Uhb = Uh + (size_t)b * NC * NS;

    // prologue: DMA K[t0] -> buf (t0&1). 16 chunks of 1 KiB, 4 per wave exactly.
    {
        const _Float16* src = kTb + (size_t)t0 * KT;
#pragma unroll
        for (int j = 0; j < 4; ++j) {
            const int ch = w * 4 + j;
            __builtin_amdgcn_global_load_lds(
                (const __attribute__((address_space(1))) void*)(src + ch * 512 + lane * 8),
                (__attribute__((address_space(3))) void*)(&Klds[t0 & 1][ch * 512]), 16, 0, 0);
        }
    }

    v8h Q[8];
    {
        const _Float16* qrow = qT + ((size_t)b * NS + nt * 64 + w * 16 + l15) * NC;
#pragma unroll
        for (int kc = 0; kc < 8; ++kc) Q[kc] = *(const v8h*)(qrow + kc * 32 + q4 * 8);
    }

    v4f O[4][4];
#pragma unroll
    for (int i = 0; i < 4; ++i)
#pragma unroll
        for (int j = 0; j < 4; ++j) O[i][j] = (v4f){0.f, 0.f, 0.f, 0.f};
    float mi[4] = {-INFINITY, -INFINITY, -INFINITY, -INFINITY};
    float li[4] = {0.f, 0.f, 0.f, 0.f};   // lane-local partial (own cols only)

    for (int t = t0; t < t1; ++t) {
        const int p = t & 1;
        const int m0 = t * 32;

        // ---- U[t] prefetch to VGPRs ----
        v8h Ur[4];
#pragma unroll
        for (int js = 0; js < 4; ++js)
            Ur[js] = *(const v8h*)(Uhb + (size_t)(w * 64 + js * 16 + l15) * NS + m0 + q4 * 8);
        asm volatile("" ::: "memory");   // pin U-before-DMA issue order (vmcnt math)

        // ---- DMA K[t+1] into other buffer; last iter wraps (uniform counts) ----
        {
            const int tn = (t + 1 < t1) ? t + 1 : t0;
            const _Float16* src = kTb + (size_t)tn * KT;
#pragma unroll
            for (int j = 0; j < 4; ++j) {
                const int ch = w * 4 + j;
                __builtin_amdgcn_global_load_lds(
                    (const __attribute__((address_space(1))) void*)(src + ch * 512 + lane * 8),
                    (__attribute__((address_space(3))) void*)(&Klds[p ^ 1][ch * 512]), 16, 0, 0);
            }
        }

        // outstanding: DMA(t)=4 oldest, U(t)=4, DMA(t+1)=4 -> retire DMA(t) only
        // (first iter: +Q(8) between DMA(t0) and U -> vmcnt(8) retires DMA+Q)
        asm volatile("s_waitcnt vmcnt(8)" ::: "memory");
        ASYNC_BARRIER();   // K[t] resident for all; Plds consumed by all

        // ---- QK^T: 16 n-rows x 32 m per wave; XOR-swizzled cols ----
        v4f sv[2];
        sv[0] = (v4f){0.f, 0.f, 0.f, 0.f};
        sv[1] = (v4f){0.f, 0.f, 0.f, 0.f};
        __builtin_amdgcn_s_setprio(1);
#pragma unroll
        for (int kc = 0; kc < 8; ++kc) {
#pragma unroll
            for (int ms = 0; ms < 2; ++ms) {
                const int rowK = ms * 16 + l15;
                const int colK = ((kc * 4 + q4) * 8) ^ ((l15 & 7) << 3);
                const v8h kf = *(const v8h*)(&Klds[p][rowK * 256 + colK]);
                sv[ms] = __builtin_amdgcn_mfma_f32_16x16x32_f16(Q[kc], kf, sv[ms], 0, 0, 0);
            }
        }
        __builtin_amdgcn_s_setprio(0);

        // ---- online softmax (base-2 domain): DPP max, lane-local li ----
        float al[4];
#pragma unroll
        for (int r = 0; r < 4; ++r) {
            const float tm = row_max16(fmaxf(sv[0][r], sv[1][r]));
            const float mn = fmaxf(mi[r], tm);
            al[r] = __builtin_amdgcn_exp2f(mi[r] - mn);
            mi[r] = mn;
            const float p0 = __builtin_amdgcn_exp2f(sv[0][r] - mn);
            const float p1 = __builtin_amdgcn_exp2f(sv[1][r] - mn);
            sv[0][r] = p0; sv[1][r] = p1;
            li[r] = li[r] * al[r] + p0 + p1;   // own 2 cols; reduced after loop
        }
        if (l15 == 0) {
#pragma unroll
            for (int r = 0; r < 4; ++r) alphaS[w * 16 + q4 * 4 + r] = al[r];
        }
        // P -> LDS fp16, plain padded rows (stride 40 halves)
#pragma unroll
        for (int ms = 0; ms < 2; ++ms)
#pragma unroll
            for (int r = 0; r < 4; ++r) {
                const int row = w * 16 + q4 * 4 + r;
                Plds[row * PSTRIDE + ms * 16 + l15] = (_Float16)sv[ms][r];
            }
        ASYNC_BARRIER();   // P/alpha visible; K[t] reads retired

        // ---- O = O*alpha + P x U ----
#pragma unroll
        for (int is = 0; is < 4; ++is) {
            const float4 av = *(const float4*)&alphaS[is * 16 + q4 * 4];
            const v4f aa = {av.x, av.y, av.z, av.w};
#pragma unroll
            for (int js = 0; js < 4; ++js) O[is][js] *= aa;
        }
        __builtin_amdgcn_s_setprio(1);
#pragma unroll
        for (int is = 0; is < 4; ++is) {
            const v8h Pf = *(const v8h*)(&Plds[(is * 16 + l15) * PSTRIDE + q4 * 8]);
#pragma unroll
            for (int js = 0; js < 4; ++js)
                O[is][js] = __builtin_amdgcn_mfma_f32_16x16x32_f16(Pf, Ur[js], O[is][js], 0, 0, 0);
        }
        __builtin_amdgcn_s_setprio(0);
    }

    // drain wrap DMA before LDS could be reassigned at s_endpgm
    asm volatile("s_waitcnt vmcnt(0)" ::: "memory");

    // ---- epilogue: reduce li across the quad-row, write stats + raw O ----
#pragma unroll
    for (int r = 0; r < 4; ++r) li[r] = row_sum16(li[r]);
    if (l15 == 0) {
#pragma unroll
        for (int r = 0; r < 4; ++r) {
            const int n = nt * 64 + w * 16 + q4 * 4 + r;
            mstat[(size_t)(s * NB + b) * NS + n] = mi[r];
            lstat[(size_t)(s * NB + b) * NS + n] = li[r];
        }
    }
#pragma unroll
    for (int is = 0; is < 4; ++is)
#pragma unroll
        for (int js = 0; js < 4; ++js)
#pragma unroll
            for (int r = 0; r < 4; ++r) {
                _Float16* dst = Ppart + ((size_t)(s * NB + b) * NS + nt * 64 + is * 16
                                         + q4 * 4 + r) * NC + w * 64 + js * 16 + l15;
                __builtin_nontemporal_store((_Float16)O[is][js][r], dst);
            }
}

// ---------------- K3: merge NSPL partials -> fp32 Opre + fused GN sums -----
// exp2 domain (m stats are log2-scaled scores).
template <int NSPL>
__global__ __launch_bounds__(256) void k_merge(const _Float16* __restrict__ Pp,
    const float* __restrict__ mstat, const float* __restrict__ lstat,
    float* __restrict__ Opre, float* __restrict__ statacc)
{
    const int b = blockIdx.y, tid = threadIdx.x;
    const int n = blockIdx.x * 8 + (tid >> 5);
    const int c0 = (tid & 31) * 8;            // == group (tid&31) exactly
    const size_t nb = (size_t)b * NS + n;
    const size_t SP = (size_t)NB * NS;

    float m[NSPL], l[NSPL];
#pragma unroll
    for (int sp = 0; sp < NSPL; ++sp) {
        m[sp] = mstat[sp * SP + nb];
        l[sp] = lstat[sp * SP + nb];
    }
    float M = m[0];
#pragma unroll
    for (int sp = 1; sp < NSPL; ++sp) M = fmaxf(M, m[sp]);
    float denom = 0.f, wgt[NSPL];
#pragma unroll
    for (int sp = 0; sp < NSPL; ++sp) {
        wgt[sp] = exp2f(m[sp] - M);
        denom += wgt[sp] * l[sp];
    }
    const float inv = 1.f / denom;

    const size_t base = nb * NC + c0;
    float v[8] = {0.f, 0.f, 0.f, 0.f, 0.f, 0.f, 0.f, 0.f};
#pragma unroll
    for (int sp = 0; sp < NSPL; ++sp) {
        const float ws = wgt[sp] * inv;
        const v8h pv = *(const v8h*)(Pp + (size_t)sp * SP * NC + base);
#pragma unroll
        for (int j = 0; j < 8; ++j) v[j] += ws * (float)pv[j];
    }
    float s1 = 0.f, s2 = 0.f;
#pragma unroll
    for (int j = 0; j < 8; ++j) { s1 += v[j]; s2 += v[j] * v[j]; }
    *(float4*)(Opre + base)     = make_float4(v[0], v[1], v[2], v[3]);
    *(float4*)(Opre + base + 4) = make_float4(v[4], v[5], v[6], v[7]);

    __shared__ float r1[256], r2[256];
    r1[tid] = s1; r2[tid] = s2;
    __syncthreads();
    if (tid < 32) {
        float a = 0.f, q = 0.f;
#pragma unroll
        for (int k = 0; k < 8; ++k) { a += r1[tid + 32 * k]; q += r2[tid + 32 * k]; }
        atomicAdd(&statacc[(b * NG + tid) * 2 + 0], a);
        atomicAdd(&statacc[(b * NG + tid) * 2 + 1], q);
    }
}

// ---------------- K4: apply GN + residual, [b][n][c] -> [b][c][n] ----------
__global__ __launch_bounds__(256) void k_gnapply(const float* __restrict__ Opre,
    const float* __restrict__ Hand, const float* __restrict__ gnw,
    const float* __restrict__ gnb, const float* __restrict__ statacc,
    float* __restrict__ out)
{
    const int nt = blockIdx.x, ct = blockIdx.y, b = blockIdx.z;
    __shared__ float buf[64 * 65];
    const int tid = threadIdx.x;
    {
        const int nr = tid >> 4, c4 = (tid & 15) * 4;
#pragma unroll
        for (int k = 0; k < 4; ++k) {
            const int n = nr + 16 * k;
            const float4 v = *(const float4*)(Opre + ((size_t)b * NS + nt * 64 + n) * NC
                                              + ct * 64 + c4);
            buf[n * 65 + c4 + 0] = v.x; buf[n * 65 + c4 + 1] = v.y;
            buf[n * 65 + c4 + 2] = v.z; buf[n * 65 + c4 + 3] = v.w;
        }
    }
    __syncthreads();
    const int nw = tid & 63, c0 = tid >> 6;
#pragma unroll
    for (int k = 0; k < 16; ++k) {
        const int cl = c0 + 4 * k;
        const int c  = ct * 64 + cl;
        const int g  = c >> 3;
        const float s1   = statacc[(b * NG + g) * 2 + 0];
        const float s2   = statacc[(b * NG + g) * 2 + 1];
        const float mean = s1 * (1.f / 32768.f);
        const float var  = s2 * (1.f / 32768.f) - mean * mean;
        const float rstd = rsqrtf(var + GEPS);
        const size_t oidx = ((size_t)b * NC + c) * NS + nt * 64 + nw;
        out[oidx] = (buf[nw * 65 + cl] - mean) * rstd * gnw[c] + gnb[c] + Hand[oidx];
    }
}

extern "C" void kernel_launch(void* const* d_in, const int* in_sizes, int n_in,
                              void* d_out, int out_size, void* d_ws, size_t ws_size,
                              hipStream_t stream)
{
    const float* Hand = (const float*)d_in[0];
    const float* U    = (const float*)d_in[1];
    const float* WHw  = (const float*)d_in[2];
    const float* WHb  = (const float*)d_in[3];
    const float* WUw  = (const float*)d_in[4];
    const float* WUb  = (const float*)d_in[5];
    const float* gnw  = (const float*)d_in[6];
    const float* gnb  = (const float*)d_in[7];
    float* out = (float*)d_out;

    // nsplit=4 needs 60,033,024 B; fall back to the proven nsplit=3 layout
    // if the workspace is tighter than that.
    const size_t NEED4 = 25952256u + 2u * 262144u + 2048u + 33554432u;
    const int nsplit = (ws_size >= NEED4) ? 4 : 3;

    char* ws = (char*)d_ws;
    _Float16* qT     = (_Float16*)(ws);                  //  8 MiB   [b][n][c]
    _Float16* kTsw   = (_Float16*)(ws + 8388608);        //  8 MiB swizzled 32-row tiles
    _Float16* Uh     = (_Float16*)(ws + 17301504);       //  8 MiB   [b][c][m]
    _Float16* Wh16   = (_Float16*)(ws + 25690112);       //  128 KiB (frag-order)
    _Float16* Wu16   = (_Float16*)(ws + 25821184);       //  128 KiB (frag-order)
    const size_t statB = (size_t)nsplit * NB * NS * 4;   // per stat array
    float*    mstat  = (float*)(ws + 25952256);
    float*    lstat  = (float*)(ws + 25952256 + statB);
    float*    statacc= (float*)(ws + 25952256 + 2 * statB);
    _Float16* Ppart  = (_Float16*)(ws + 25952256 + 2 * statB + 2048);
    float*    Opre   = (float*)(ws);                     //  16 MiB alias (qT+kTsw dead)

    hipMemsetAsync(statacc, 0, NB * NG * 2 * sizeof(float), stream);
    k_convert<<<dim3((NC * NC) / 256), 256, 0, stream>>>(WHw, WUw, Wh16, Wu16);
    k_qkgemm <<<dim3(64, NB, 2), 256, 0, stream>>>(Hand, U, Wh16, Wu16, WHb, WUb, qT, kTsw, Uh);
    if (nsplit == 4) {
        k_attn<4> <<<dim3(NB, 64, 4), 256, 0, stream>>>(qT, kTsw, Uh, Ppart, mstat, lstat);
        k_merge<4><<<dim3(NS / 8, NB), 256, 0, stream>>>(Ppart, mstat, lstat, Opre, statacc);
    } else {
        k_attn<3> <<<dim3(NB, 64, 3), 256, 0, stream>>>(qT, kTsw, Uh, Ppart, mstat, lstat);
        k_merge<3><<<dim3(NS / 8, NB), 256, 0, stream>>>(Ppart, mstat, lstat, Opre, statacc);
    }
    k_gnapply<<<dim3(64, 4, NB), 256, 0, stream>>>(Opre, Hand, gnw, gnb, statacc, out);
}

// Round 5
// 267.159 us; speedup vs baseline: 1.4736x; 1.1118x over previous
//
#include <hip/hip_runtime.h>
#include <hip/hip_fp16.h>
#include <math.h>

// CrossFeatureAffinityPooling on gfx950 — R11
// Post-mortems: R8/R9/R10 establish residency is capped at 3 blocks/CU by the
// UNIFIED VGPR+AGPR file (84 VGPR + ~72 AGPR ≈ 148 > 128), not LDS. So:
//   - revert to NSPLIT=3 (768 blocks = 3/CU, ZERO tail; nsplit=4 was pure tail pain)
//   - revert K layout to padded KSTRIDE=272 (2.1M conflicts vs XOR's 10.5M)
// New: software-pipelined PV. Single barrier/iter; PV(t-1) runs right after the
// barrier IN PARALLEL with softmax(t) (MFMA pipe ∥ VALU pipe, m114). Plds/alphaS
// double-buffered; Ur single-buffered (loaded after PV consumes the old set).
// DMA(t+1) issued post-barrier(t), retired pre-barrier(t+1): full-phase cover
// (the R7 failure was waiting on a same-iteration DMA). Barriers/block 86 -> 44.

typedef _Float16 v8h __attribute__((ext_vector_type(8)));
typedef float    v4f __attribute__((ext_vector_type(4)));

#define NB 4
#define NC 256
#define NS 4096
#define NG 32
#define GEPS 1e-5f
#define NSPLIT 3
#define KSTRIDE 272            // halves per K-tile row (256 data + 16 pad)
#define KTILE   8704           // halves per 32-row K tile (17408 B = 17 KiB)
#define PSTRIDE 40             // halves per P row (32 data + 8 pad)
#define LOG2E   1.44269504f

// raw barrier: LDS-visibility only (lgkm drain), vmem stays in flight
#define ASYNC_BARRIER() asm volatile("s_waitcnt lgkmcnt(0)\n\ts_barrier" ::: "memory")

// DPP rotation-reduce within each 16-lane row (the l15 domain of MFMA quads)
template <int CTRL>
__device__ __forceinline__ float dpp_rot(float x) {
    int r = __builtin_amdgcn_update_dpp(__float_as_int(x), __float_as_int(x),
                                        CTRL, 0xF, 0xF, false);
    return __int_as_float(r);
}
__device__ __forceinline__ float row_max16(float x) {
    x = fmaxf(x, dpp_rot<0x128>(x));
    x = fmaxf(x, dpp_rot<0x124>(x));
    x = fmaxf(x, dpp_rot<0x122>(x));
    x = fmaxf(x, dpp_rot<0x121>(x));
    return x;
}
__device__ __forceinline__ float row_sum16(float x) {
    x = x + dpp_rot<0x128>(x);
    x = x + dpp_rot<0x124>(x);
    x = x + dpp_rot<0x122>(x);
    x = x + dpp_rot<0x121>(x);
    return x;
}

// ---------------- K0: convert weights into MFMA-frag order (W only) --------
__global__ __launch_bounds__(256) void k_convert(const float* __restrict__ Wh,
    const float* __restrict__ Wu, _Float16* __restrict__ Wh16, _Float16* __restrict__ Wu16)
{
    const int i = blockIdx.x * 256 + threadIdx.x;   // i < NC*NC
    const int o = i >> 8, c = i & 255;
    const int idx = ((((o >> 4) * 8 + (c >> 5)) * 4 + ((c >> 3) & 3)) * 16
                     + (o & 15)) * 8 + (c & 7);
    Wh16[idx] = (_Float16)Wh[i];
    Wu16[idx] = (_Float16)Wu[i];
}

// ---------------- K1: q^T / k^T GEMM (+ fused Uh materialization) ----------
__global__ __launch_bounds__(256) void k_qkgemm(const float* __restrict__ Hand,
    const float* __restrict__ U, const _Float16* __restrict__ Wh16,
    const _Float16* __restrict__ Wu16, const float* __restrict__ WHb,
    const float* __restrict__ WUb, _Float16* __restrict__ qT,
    _Float16* __restrict__ kTsw, _Float16* __restrict__ Uh)
{
    const int nt = blockIdx.x, b = blockIdx.y, z = blockIdx.z;
    const float*    X    = z ? U    : Hand;
    const _Float16* W    = z ? Wu16 : Wh16;
    const float*    bias = z ? WUb  : WHb;

    const int tid = threadIdx.x, w = tid >> 6, lane = tid & 63;
    const int q4 = lane >> 4, l15 = lane & 15;
    const int n = nt * 64 + w * 16 + l15;

    const float* Xcol = X + (size_t)b * NC * NS + n;
    v8h A[8];
#pragma unroll
    for (int kc = 0; kc < 8; ++kc) {
        const int c0 = kc * 32 + q4 * 8;
        v8h a;
#pragma unroll
        for (int j = 0; j < 8; ++j) a[j] = (_Float16)Xcol[(size_t)(c0 + j) * NS];
        A[kc] = a;
    }

    // fused: z=1 blocks hold U^T[n][c] fp16 frags -> write Uh[b][c][n]
    if (z == 1) {
        _Float16* ub = Uh + (size_t)b * NC * NS + n;
#pragma unroll
        for (int kc = 0; kc < 8; ++kc) {
            const int c0 = kc * 32 + q4 * 8;
#pragma unroll
            for (int j = 0; j < 8; ++j) ub[(size_t)(c0 + j) * NS] = A[kc][j];
        }
    }

#pragma unroll 4
    for (int osub = 0; osub < 16; ++osub) {
        const int o = osub * 16 + l15;
        v4f acc = {0.f, 0.f, 0.f, 0.f};
#pragma unroll
        for (int kc = 0; kc < 8; ++kc) {
            // pre-swizzled W: wave reads 1 KB contiguous, lane-coalesced b128
            const v8h bf = *(const v8h*)(W + ((size_t)(osub * 8 + kc) * 64 + lane) * 8);
            acc = __builtin_amdgcn_mfma_f32_16x16x32_f16(A[kc], bf, acc, 0, 0, 0);
        }
        const float bv = bias[o];
        if (z == 0) {
            // q scaled by log2e -> softmax runs in base-2 (raw v_exp_f32)
            _Float16* orow = qT + ((size_t)b * NS + nt * 64 + w * 16 + q4 * 4) * NC + o;
#pragma unroll
            for (int r = 0; r < 4; ++r)
                orow[(size_t)r * NC] = (_Float16)((acc[r] + bv) * LOG2E);
        } else {
            _Float16* kb = kTsw + (size_t)b * 128 * KTILE;
#pragma unroll
            for (int r = 0; r < 4; ++r) {
                const int m = nt * 64 + w * 16 + q4 * 4 + r;
                kb[(size_t)(m >> 5) * KTILE + (m & 31) * KSTRIDE + o] = (_Float16)(acc[r] + bv);
            }
        }
    }
}

// ---------------- K2: flash attention partial, pipelined single-barrier ----
template <int NSPL>
__global__ __launch_bounds__(256, 3) void k_attn(const _Float16* __restrict__ qT,
    const _Float16* __restrict__ kTsw, const _Float16* __restrict__ Uh,
    _Float16* __restrict__ Ppart, float* __restrict__ mstat, float* __restrict__ lstat)
{
    const int b  = blockIdx.x;
    const int nt = blockIdx.y;
    const int s  = blockIdx.z;
    const int t0 = (s * 128) / NSPL;
    const int t1 = ((s + 1) * 128) / NSPL;

    __shared__ __align__(16) _Float16 Klds[2][KTILE];        // 2 x 17 KiB, padded
    __shared__ __align__(16) _Float16 Plds[2][64 * PSTRIDE]; // 2 x 5 KiB, padded
    __shared__ __align__(16) float alphaS[2][64];

    const int tid = threadIdx.x, w = tid >> 6, lane = tid & 63;
    const int q4 = lane >> 4, l15 = lane & 15;

    const _Float16* kTb = kTsw + (size_t)b * 128 * KTILE;
    const _Float16* Uhb = Uh + (size_t)b * NC * NS;

    v8h Q[8];
    v8h Ur[4];
    v4f O[4][4];
    v4f sv[2];
    float mi[4] = {-INFINITY, -INFINITY, -INFINITY, -INFINITY};
    float li[4] = {0.f, 0.f, 0.f, 0.f};   // lane-local partial (own cols only)

    // DMA one 32-row K tile (17 chunks of 1 KiB; 5 per wave via (w*5+j)%17,
    // chunks 0..2 double-copied -> uniform 5 outstanding per wave)
    auto DMA = [&](int t, int kb) {
        const _Float16* src = kTb + (size_t)t * KTILE;
#pragma unroll
        for (int j = 0; j < 5; ++j) {
            const int ch = (w * 5 + j) % 17;
            __builtin_amdgcn_global_load_lds(
                (const __attribute__((address_space(1))) void*)(src + ch * 512 + lane * 8),
                (__attribute__((address_space(3))) void*)(&Klds[kb][ch * 512]), 16, 0, 0);
        }
    };
    // QK^T from Klds[kb]: 16 n-rows x 32 m per wave
    auto QK = [&](int kb) {
        sv[0] = (v4f){0.f, 0.f, 0.f, 0.f};
        sv[1] = (v4f){0.f, 0.f, 0.f, 0.f};
        __builtin_amdgcn_s_setprio(1);
#pragma unroll
        for (int kc = 0; kc < 8; ++kc) {
#pragma unroll
            for (int ms = 0; ms < 2; ++ms) {
                const v8h kf = *(const v8h*)(&Klds[kb][(ms * 16 + l15) * KSTRIDE
                                             + (kc * 4 + q4) * 8]);
                sv[ms] = __builtin_amdgcn_mfma_f32_16x16x32_f16(Q[kc], kf, sv[ms], 0, 0, 0);
            }
        }
        __builtin_amdgcn_s_setprio(0);
    };
    // online softmax (base-2) on sv, write P/alpha into buffer pb
    auto SMAX = [&](int pb) {
        float al[4];
#pragma unroll
        for (int r = 0; r < 4; ++r) {
            const float tm = row_max16(fmaxf(sv[0][r], sv[1][r]));
            const float mn = fmaxf(mi[r], tm);
            al[r] = __builtin_amdgcn_exp2f(mi[r] - mn);
            mi[r] = mn;
            const float p0 = __builtin_amdgcn_exp2f(sv[0][r] - mn);
            const float p1 = __builtin_amdgcn_exp2f(sv[1][r] - mn);
            sv[0][r] = p0; sv[1][r] = p1;
            li[r] = li[r] * al[r] + p0 + p1;
        }
        if (l15 == 0) {
#pragma unroll
            for (int r = 0; r < 4; ++r) alphaS[pb][w * 16 + q4 * 4 + r] = al[r];
        }
#pragma unroll
        for (int ms = 0; ms < 2; ++ms)
#pragma unroll
            for (int r = 0; r < 4; ++r) {
                const int row = w * 16 + q4 * 4 + r;
                Plds[pb][row * PSTRIDE + ms * 16 + l15] = (_Float16)sv[ms][r];
            }
    };
    // O = O*alpha + P x U, reading buffer pb (written LAST iteration)
    auto PV = [&](int pb) {
#pragma unroll
        for (int is = 0; is < 4; ++is) {
            const float4 av = *(const float4*)&alphaS[pb][is * 16 + q4 * 4];
            const v4f aa = {av.x, av.y, av.z, av.w};
#pragma unroll
            for (int js = 0; js < 4; ++js) O[is][js] *= aa;
        }
        __builtin_amdgcn_s_setprio(1);
#pragma unroll
        for (int is = 0; is < 4; ++is) {
            const v8h Pf = *(const v8h*)(&Plds[pb][(is * 16 + l15) * PSTRIDE + q4 * 8]);
#pragma unroll
            for (int js = 0; js < 4; ++js)
                O[is][js] = __builtin_amdgcn_mfma_f32_16x16x32_f16(Pf, Ur[js], O[is][js], 0, 0, 0);
        }
        __builtin_amdgcn_s_setprio(0);
    };
    auto ULOAD = [&](int t) {
#pragma unroll
        for (int js = 0; js < 4; ++js)
            Ur[js] = *(const v8h*)(Uhb + (size_t)(w * 64 + js * 16 + l15) * NS
                                   + t * 32 + q4 * 8);
    };

#pragma unroll
    for (int i = 0; i < 4; ++i)
#pragma unroll
        for (int j = 0; j < 4; ++j) O[i][j] = (v4f){0.f, 0.f, 0.f, 0.f};

    // ---- prologue: DMA K[t0]; Q; QK(t0); DMA K[t0+1]; softmax(t0); U[t0] ----
    DMA(t0, 0);
    asm volatile("" ::: "memory");
    {
        const _Float16* qrow = qT + ((size_t)b * NS + nt * 64 + w * 16 + l15) * NC;
#pragma unroll
        for (int kc = 0; kc < 8; ++kc) Q[kc] = *(const v8h*)(qrow + kc * 32 + q4 * 8);
    }
    asm volatile("" ::: "memory");
    asm volatile("s_waitcnt vmcnt(8)" ::: "memory");   // retire DMA(t0), keep Q(8)
    ASYNC_BARRIER();                                    // K[t0] resident
    QK(0);
    DMA((t0 + 1 < t1) ? t0 + 1 : t0, 1);
    asm volatile("" ::: "memory");
    SMAX(0);
    ULOAD(t0);

    // ---- main loop: one barrier per tile; PV(t-1) overlaps softmax(t) ----
    for (int t = t0 + 1; t < t1; ++t) {
        const int e = (t - t0) & 1;
        // outstanding: DMA(t)=5 oldest, U(t-1)=4 -> retire DMA(t) only
        asm volatile("s_waitcnt vmcnt(4)" ::: "memory");
        ASYNC_BARRIER();   // K[t] resident; P/alpha[e^1] visible; p^1-reads retired
        QK(e);
        DMA((t + 1 < t1) ? t + 1 : t0, e ^ 1);          // post-barrier issue (safe)
        asm volatile("" ::: "memory");
        PV(e ^ 1);         // MFMA pipe: finish tile t-1
        SMAX(e);           // VALU pipe: softmax tile t (other waves' PV overlaps)
        ULOAD(t);          // U[t] for PV(t) next iter (old Ur just consumed)
    }

    // ---- epilogue: finish PV(t1-1); drain wrap DMA ----
    asm volatile("s_waitcnt vmcnt(0)" ::: "memory");
    ASYNC_BARRIER();       // Plds/alphaS of last tile visible
    PV((t1 - 1 - t0) & 1);

    // reduce li across the quad-row, write stats + raw O
#pragma unroll
    for (int r = 0; r < 4; ++r) li[r] = row_sum16(li[r]);
    if (l15 == 0) {
#pragma unroll
        for (int r = 0; r < 4; ++r) {
            const int n = nt * 64 + w * 16 + q4 * 4 + r;
            mstat[(size_t)(s * NB + b) * NS + n] = mi[r];
            lstat[(size_t)(s * NB + b) * NS + n] = li[r];
        }
    }
#pragma unroll
    for (int is = 0; is < 4; ++is)
#pragma unroll
        for (int js = 0; js < 4; ++js)
#pragma unroll
            for (int r = 0; r < 4; ++r) {
                _Float16* dst = Ppart + ((size_t)(s * NB + b) * NS + nt * 64 + is * 16
                                         + q4 * 4 + r) * NC + w * 64 + js * 16 + l15;
                __builtin_nontemporal_store((_Float16)O[is][js][r], dst);
            }
}

// ---------------- K3: merge NSPL partials -> fp32 Opre + fused GN sums -----
// exp2 domain (m stats are log2-scaled scores).
template <int NSPL>
__global__ __launch_bounds__(256) void k_merge(const _Float16* __restrict__ Pp,
    const float* __restrict__ mstat, const float* __restrict__ lstat,
    float* __restrict__ Opre, float* __restrict__ statacc)
{
    const int b = blockIdx.y, tid = threadIdx.x;
    const int n = blockIdx.x * 8 + (tid >> 5);
    const int c0 = (tid & 31) * 8;            // == group (tid&31) exactly
    const size_t nb = (size_t)b * NS + n;
    const size_t SP = (size_t)NB * NS;

    float m[NSPL], l[NSPL];
#pragma unroll
    for (int sp = 0; sp < NSPL; ++sp) {
        m[sp] = mstat[sp * SP + nb];
        l[sp] = lstat[sp * SP + nb];
    }
    float M = m[0];
#pragma unroll
    for (int sp = 1; sp < NSPL; ++sp) M = fmaxf(M, m[sp]);
    float denom = 0.f, wgt[NSPL];
#pragma unroll
    for (int sp = 0; sp < NSPL; ++sp) {
        wgt[sp] = exp2f(m[sp] - M);
        denom += wgt[sp] * l[sp];
    }
    const float inv = 1.f / denom;

    const size_t base = nb * NC + c0;
    float v[8] = {0.f, 0.f, 0.f, 0.f, 0.f, 0.f, 0.f, 0.f};
#pragma unroll
    for (int sp = 0; sp < NSPL; ++sp) {
        const float ws = wgt[sp] * inv;
        const v8h pv = *(const v8h*)(Pp + (size_t)sp * SP * NC + base);
#pragma unroll
        for (int j = 0; j < 8; ++j) v[j] += ws * (float)pv[j];
    }
    float s1 = 0.f, s2 = 0.f;
#pragma unroll
    for (int j = 0; j < 8; ++j) { s1 += v[j]; s2 += v[j] * v[j]; }
    *(float4*)(Opre + base)     = make_float4(v[0], v[1], v[2], v[3]);
    *(float4*)(Opre + base + 4) = make_float4(v[4], v[5], v[6], v[7]);

    __shared__ float r1[256], r2[256];
    r1[tid] = s1; r2[tid] = s2;
    __syncthreads();
    if (tid < 32) {
        float a = 0.f, q = 0.f;
#pragma unroll
        for (int k = 0; k < 8; ++k) { a += r1[tid + 32 * k]; q += r2[tid + 32 * k]; }
        atomicAdd(&statacc[(b * NG + tid) * 2 + 0], a);
        atomicAdd(&statacc[(b * NG + tid) * 2 + 1], q);
    }
}

// ---------------- K4: apply GN + residual, [b][n][c] -> [b][c][n] ----------
__global__ __launch_bounds__(256) void k_gnapply(const float* __restrict__ Opre,
    const float* __restrict__ Hand, const float* __restrict__ gnw,
    const float* __restrict__ gnb, const float* __restrict__ statacc,
    float* __restrict__ out)
{
    const int nt = blockIdx.x, ct = blockIdx.y, b = blockIdx.z;
    __shared__ float buf[64 * 65];
    const int tid = threadIdx.x;
    {
        const int nr = tid >> 4, c4 = (tid & 15) * 4;
#pragma unroll
        for (int k = 0; k < 4; ++k) {
            const int n = nr + 16 * k;
            const float4 v = *(const float4*)(Opre + ((size_t)b * NS + nt * 64 + n) * NC
                                              + ct * 64 + c4);
            buf[n * 65 + c4 + 0] = v.x; buf[n * 65 + c4 + 1] = v.y;
            buf[n * 65 + c4 + 2] = v.z; buf[n * 65 + c4 + 3] = v.w;
        }
    }
    __syncthreads();
    const int nw = tid & 63, c0 = tid >> 6;
#pragma unroll
    for (int k = 0; k < 16; ++k) {
        const int cl = c0 + 4 * k;
        const int c  = ct * 64 + cl;
        const int g  = c >> 3;
        const float s1   = statacc[(b * NG + g) * 2 + 0];
        const float s2   = statacc[(b * NG + g) * 2 + 1];
        const float mean = s1 * (1.f / 32768.f);
        const float var  = s2 * (1.f / 32768.f) - mean * mean;
        const float rstd = rsqrtf(var + GEPS);
        const size_t oidx = ((size_t)b * NC + c) * NS + nt * 64 + nw;
        out[oidx] = (buf[nw * 65 + cl] - mean) * rstd * gnw[c] + gnb[c] + Hand[oidx];
    }
}

extern "C" void kernel_launch(void* const* d_in, const int* in_sizes, int n_in,
                              void* d_out, int out_size, void* d_ws, size_t ws_size,
                              hipStream_t stream)
{
    const float* Hand = (const float*)d_in[0];
    const float* U    = (const float*)d_in[1];
    const float* WHw  = (const float*)d_in[2];
    const float* WHb  = (const float*)d_in[3];
    const float* WUw  = (const float*)d_in[4];
    const float* WUb  = (const float*)d_in[5];
    const float* gnw  = (const float*)d_in[6];
    const float* gnb  = (const float*)d_in[7];
    float* out = (float*)d_out;

    // workspace (~49.1 MiB). Opre(fp32,16Mi) ALIASES qT + kTsw head (dead post-attn).
    char* ws = (char*)d_ws;
    _Float16* qT     = (_Float16*)(ws);                  //  8 MiB   [b][n][c]
    _Float16* kTsw   = (_Float16*)(ws + 8388608);        //  8.5 MiB padded 32-row tiles
    _Float16* Uh     = (_Float16*)(ws + 17301504);       //  8 MiB   [b][c][m]
    _Float16* Wh16   = (_Float16*)(ws + 25690112);       //  128 KiB (frag-order)
    _Float16* Wu16   = (_Float16*)(ws + 25821184);       //  128 KiB (frag-order)
    float*    mstat  = (float*)(ws + 25952256);          //  192 KiB [3][b][n]
    float*    lstat  = (float*)(ws + 26148864);          //  192 KiB
    float*    statacc= (float*)(ws + 26345472);          //  2 KiB [b][g][2]
    _Float16* Ppart  = (_Float16*)(ws + 26347520);       //  24 MiB [3][b][n][c]
    float*    Opre   = (float*)(ws);                     //  16 MiB alias

    hipMemsetAsync(statacc, 0, NB * NG * 2 * sizeof(float), stream);
    k_convert<<<dim3((NC * NC) / 256), 256, 0, stream>>>(WHw, WUw, Wh16, Wu16);
    k_qkgemm <<<dim3(64, NB, 2), 256, 0, stream>>>(Hand, U, Wh16, Wu16, WHb, WUb, qT, kTsw, Uh);
    k_attn<NSPLIT>   <<<dim3(NB, 64, NSPLIT), 256, 0, stream>>>(qT, kTsw, Uh, Ppart, mstat, lstat);
    k_merge<NSPLIT>  <<<dim3(NS / 8, NB), 256, 0, stream>>>(Ppart, mstat, lstat, Opre, statacc);
    k_gnapply<<<dim3(64, 4, NB), 256, 0, stream>>>(Opre, Hand, gnw, gnb, statacc, out);
}